// Round 1
// baseline (943.980 us; speedup 1.0000x reference)
//
#include <hip/hip_runtime.h>
#include <stdint.h>

// SparseMoE: B=4,S=2048,D=1024,E=8,H=2048, top-k=2.
// Outputs (concat, float32): final_output[8192*1024], top_k_indices[8192*2] (as floats), aux_loss[1].

#define NTOK   8192
#define DIM    1024
#define NEXP   8
#define HID    2048
#define OUT_MAIN (NTOK * DIM)          // 8388608
#define IDX_OFF  OUT_MAIN
#define AUX_OFF  (OUT_MAIN + NTOK * 2) // 8404992

typedef __attribute__((ext_vector_type(8))) short short8;
typedef __attribute__((ext_vector_type(4))) float floatx4;

__device__ __forceinline__ unsigned short f2bf(float f) {
  unsigned int b = __float_as_uint(f);
  b += 0x7FFFu + ((b >> 16) & 1u);      // RNE; inputs finite
  return (unsigned short)(b >> 16);
}

// ---------------- gating: logits (fp64 acc), top-2, masked softmax, scatter, xb=bf16(x) ---
__global__ __launch_bounds__(256) void k_gating(
    const float* __restrict__ x, const float* __restrict__ gate_w,
    const float* __restrict__ gate_b, const float* __restrict__ noise,
    float* __restrict__ out, int* __restrict__ counts,
    int* __restrict__ lists_tok, float* __restrict__ lists_p,
    float* __restrict__ probs_all, unsigned short* __restrict__ xb)
{
  const int lane = threadIdx.x & 63;
  const int wv   = threadIdx.x >> 6;
  const int t    = blockIdx.x * 4 + wv;           // one token per wave
  const float* xr = x + (size_t)t * DIM;
  double acc[NEXP] = {0,0,0,0,0,0,0,0};
  #pragma unroll
  for (int jj = 0; jj < 4; ++jj) {
    const int d0 = lane * 4 + jj * 256;
    const float4 xv = *(const float4*)(xr + d0);
    const float xs[4] = {xv.x, xv.y, xv.z, xv.w};
    unsigned short xbq[4];
    #pragma unroll
    for (int c = 0; c < 4; ++c) {
      const float4 g0 = *(const float4*)(gate_w + (size_t)(d0 + c) * NEXP);
      const float4 g1 = *(const float4*)(gate_w + (size_t)(d0 + c) * NEXP + 4);
      const double xd = (double)xs[c];
      acc[0] += xd * (double)g0.x; acc[1] += xd * (double)g0.y;
      acc[2] += xd * (double)g0.z; acc[3] += xd * (double)g0.w;
      acc[4] += xd * (double)g1.x; acc[5] += xd * (double)g1.y;
      acc[6] += xd * (double)g1.z; acc[7] += xd * (double)g1.w;
      xbq[c] = f2bf(xs[c]);
    }
    if (xb) {
      ushort4 q; q.x = xbq[0]; q.y = xbq[1]; q.z = xbq[2]; q.w = xbq[3];
      *(ushort4*)(xb + (size_t)t * DIM + d0) = q;
    }
  }
  #pragma unroll
  for (int e = 0; e < NEXP; ++e) {
    #pragma unroll
    for (int off = 32; off; off >>= 1) acc[e] += __shfl_xor(acc[e], off);
  }
  if (lane == 0) {
    double l[NEXP];
    #pragma unroll
    for (int e = 0; e < NEXP; ++e)
      l[e] = acc[e] + (double)gate_b[e] + 0.01 * (double)noise[(size_t)t * NEXP + e];
    // top-2 with jax.lax.top_k tie semantics (stable desc: earliest index wins)
    int i1 = 0; double v1 = l[0];
    #pragma unroll
    for (int e = 1; e < NEXP; ++e) if (l[e] > v1) { v1 = l[e]; i1 = e; }
    int i2 = (i1 == 0) ? 1 : 0; double v2 = l[i2];
    #pragma unroll
    for (int e = 0; e < NEXP; ++e) if (e != i1 && l[e] > v2) { v2 = l[e]; i2 = e; }
    // masked softmax over all 8 (mask = logit >= v2), max is v1
    float pr[NEXP]; float Z = 0.f;
    #pragma unroll
    for (int e = 0; e < NEXP; ++e) {
      const float a = (l[e] >= v2) ? (float)(l[e] - v1) : -1.0e9f;
      pr[e] = __expf(a); Z += pr[e];
    }
    const float rz = 1.0f / Z;
    #pragma unroll
    for (int e = 0; e < NEXP; ++e) {
      pr[e] *= rz;
      probs_all[(size_t)t * NEXP + e] = pr[e];
    }
    out[(size_t)IDX_OFF + t * 2]     = (float)i1;
    out[(size_t)IDX_OFF + t * 2 + 1] = (float)i2;
    int p1 = atomicAdd(&counts[i1], 1);
    lists_tok[i1 * NTOK + p1] = t; lists_p[i1 * NTOK + p1] = pr[i1];
    int p2 = atomicAdd(&counts[i2], 1);
    lists_tok[i2 * NTOK + p2] = t; lists_p[i2 * NTOK + p2] = pr[i2];
  }
}

__global__ void k_offs(const int* __restrict__ counts, int* __restrict__ offs) {
  if (threadIdx.x == 0) {
    int a = 0;
    #pragma unroll
    for (int e = 0; e < NEXP; ++e) { offs[e] = a; a += counts[e]; }
    offs[NEXP] = a;
  }
}

// ---------------- aux loss ----------------
__global__ __launch_bounds__(256) void k_aux(const float* __restrict__ probs_all,
                                             float* __restrict__ out) {
  float p[NEXP] = {0,0,0,0,0,0,0,0};
  for (int t = threadIdx.x; t < NTOK; t += 256) {
    const float4 a = *(const float4*)(probs_all + (size_t)t * NEXP);
    const float4 b = *(const float4*)(probs_all + (size_t)t * NEXP + 4);
    p[0] += a.x; p[1] += a.y; p[2] += a.z; p[3] += a.w;
    p[4] += b.x; p[5] += b.y; p[6] += b.z; p[7] += b.w;
  }
  #pragma unroll
  for (int e = 0; e < NEXP; ++e) {
    #pragma unroll
    for (int off = 32; off; off >>= 1) p[e] += __shfl_xor(p[e], off);
  }
  __shared__ float red[4][NEXP];
  const int lane = threadIdx.x & 63, wv = threadIdx.x >> 6;
  if (lane == 0) {
    #pragma unroll
    for (int e = 0; e < NEXP; ++e) red[wv][e] = p[e];
  }
  __syncthreads();
  if (threadIdx.x == 0) {
    float usage[NEXP], s = 0.f;
    #pragma unroll
    for (int e = 0; e < NEXP; ++e) {
      usage[e] = red[0][e] + red[1][e] + red[2][e] + red[3][e];
      s += usage[e];
    }
    float imp[NEXP], mean = 0.f, var = 0.f;
    #pragma unroll
    for (int e = 0; e < NEXP; ++e) { imp[e] = usage[e] / s; mean += imp[e]; }
    mean *= 0.125f;
    #pragma unroll
    for (int e = 0; e < NEXP; ++e) { const float d = imp[e] - mean; var += d * d; }
    var *= 0.125f;
    out[AUX_OFF] = sqrtf(var) / (mean + 1e-10f);
  }
}

// ---------------- grouped MFMA GEMM ----------------
// MODE 0: h[slot, nb+n] = silu( xb[tok] @ w1[e][:, hb+nb+n] + b1 )      (K = 1024)
// MODE 1: out[tok, nb+n] += p * ( h[slot] @ w2[e][hb: , nb+n] + b2 )    (K = Hs)
// 128x128 tile, 4 waves (2x2), 16x16x32 bf16 MFMA, BK=64.
// A staged via global_load_lds (16B/lane). B transpose+converted fp32->bf16 into
// XOR-swizzled LDS [n][k] (8B-chunk swizzle: chunk (n,c) at n*128 + ((c^(n&15))<<3)).
template <int MODE>
__global__ __launch_bounds__(256) void k_gemm(
    const unsigned short* __restrict__ Abase,
    const float* __restrict__ Bsrc, const float* __restrict__ bias,
    const int* __restrict__ counts, const int* __restrict__ offs,
    const int* __restrict__ lists_tok, const float* __restrict__ lists_p,
    unsigned short* __restrict__ hout, float* __restrict__ out,
    const int hb, const int Hs)
{
  const int e   = blockIdx.z;
  const int n_e = counts[e];
  const int m0  = blockIdx.x * 128;
  if (m0 >= n_e) return;
  const int nb   = blockIdx.y * 128;
  const int tid  = threadIdx.x;
  const int lane = tid & 63;
  const int wv   = tid >> 6;
  const int wm   = (wv & 1) << 6;
  const int wn   = (wv >> 1) << 6;

  __shared__ __align__(16) unsigned short as[128 * 64];  // A tile [row][k], 16 KB
  __shared__ __align__(16) unsigned char  bs[128 * 128]; // B^T tile swizzled, 16 KB

  const int    K    = (MODE == 0) ? DIM : Hs;
  const size_t ldb  = (MODE == 0) ? (size_t)HID : (size_t)DIM;
  const float* Bcol = Bsrc + (size_t)e * (DIM * HID) + ((MODE == 0) ? (hb + nb) : nb);
  const int    br0  = (MODE == 0) ? 0 : hb;

  floatx4 acc[4][4];
  #pragma unroll
  for (int i = 0; i < 4; ++i)
    #pragma unroll
    for (int j = 0; j < 4; ++j) acc[i][j] = (floatx4){0.f, 0.f, 0.f, 0.f};

  for (int kk = 0; kk < K; kk += 64) {
    __syncthreads();
    // stage A: 8 rows per instr (8 lanes x 16B per row)
    #pragma unroll
    for (int ii = 0; ii < 4; ++ii) {
      const int r  = (wv << 5) + (ii << 3) + (lane >> 3);
      const int rc = (m0 + r < n_e) ? (m0 + r) : (n_e - 1);
      size_t arow;
      if (MODE == 0) arow = (size_t)lists_tok[e * NTOK + rc] * DIM;
      else           arow = (size_t)(offs[e] + rc) * Hs;
      const unsigned short* gp = Abase + arow + kk + ((lane & 7) << 3);
      unsigned short* lp = as + (((wv << 5) + (ii << 3)) << 6);   // wave-uniform base
      __builtin_amdgcn_global_load_lds(
          (const __attribute__((address_space(1))) void*)gp,
          (__attribute__((address_space(3))) void*)(void*)lp, 16, 0, 0);
    }
    // stage B: transpose+convert; each thread: 16 x (2 scalar fp32 loads -> packed b32 write)
    #pragma unroll
    for (int i = 0; i < 16; ++i) {
      const int k = ((wv << 3) + (i & 7)) << 1;          // even k, pairs (k, k+1)
      const int n = lane + ((i >> 3) << 6);
      const float* bp = Bcol + (size_t)(br0 + kk + k) * ldb + n;
      const float f0 = bp[0];
      const float f1 = bp[ldb];
      const unsigned int pk = (unsigned int)f2bf(f0) | ((unsigned int)f2bf(f1) << 16);
      const int sw = ((k >> 2) ^ (n & 15));
      *(unsigned int*)(bs + n * 128 + (sw << 3) + ((k & 3) << 1)) = pk;
    }
    __syncthreads();
    // compute
    #pragma unroll
    for (int ks = 0; ks < 2; ++ks) {
      const int k0 = (ks << 5) + ((lane >> 4) << 3);
      short8 af[4];
      #pragma unroll
      for (int i = 0; i < 4; ++i) {
        const int row = wm + (i << 4) + (lane & 15);
        af[i] = *(const short8*)((const short*)as + row * 64 + k0);
      }
      short8 bfr[4];
      #pragma unroll
      for (int j = 0; j < 4; ++j) {
        const int n  = wn + (j << 4) + (lane & 15);
        const int c0 = k0 >> 2;
        union { unsigned int u[4]; short8 s; } tmp;
        *(uint2*)&tmp.u[0] = *(const uint2*)(bs + n * 128 + (((c0)     ^ (n & 15)) << 3));
        *(uint2*)&tmp.u[2] = *(const uint2*)(bs + n * 128 + (((c0 + 1) ^ (n & 15)) << 3));
        bfr[j] = tmp.s;
      }
      #pragma unroll
      for (int i = 0; i < 4; ++i)
        #pragma unroll
        for (int j = 0; j < 4; ++j)
          acc[i][j] = __builtin_amdgcn_mfma_f32_16x16x32_bf16(af[i], bfr[j], acc[i][j], 0, 0, 0);
    }
  }

  // epilogue: C/D map col=lane&15, row=(lane>>4)*4+r (m89-verified)
  const int q4 = (lane >> 4) << 2;
  if (MODE == 0) {
    #pragma unroll
    for (int i = 0; i < 4; ++i) {
      #pragma unroll
      for (int j = 0; j < 4; ++j) {
        const int nloc = wn + (j << 4) + (lane & 15);
        const float bb = bias[e * HID + hb + nb + nloc];
        #pragma unroll
        for (int r = 0; r < 4; ++r) {
          const int m = m0 + wm + (i << 4) + q4 + r;
          if (m < n_e) {
            float v = acc[i][j][r] + bb;
            v = v / (1.0f + __expf(-v));                 // silu
            hout[(size_t)(offs[e] + m) * Hs + nb + nloc] = f2bf(v);
          }
        }
      }
    }
  } else {
    #pragma unroll
    for (int i = 0; i < 4; ++i) {
      #pragma unroll
      for (int r = 0; r < 4; ++r) {
        const int m = m0 + wm + (i << 4) + q4 + r;
        if (m < n_e) {
          const int   tok = lists_tok[e * NTOK + m];
          const float p   = lists_p[e * NTOK + m];
          #pragma unroll
          for (int j = 0; j < 4; ++j) {
            const int d = nb + wn + (j << 4) + (lane & 15);
            float v = acc[i][j][r];
            if (hb == 0) v += bias[e * DIM + d];         // add b2 once (first H-slice)
            atomicAdd(out + (size_t)tok * DIM + d, p * v);
          }
        }
      }
    }
  }
}

extern "C" void kernel_launch(void* const* d_in, const int* in_sizes, int n_in,
                              void* d_out, int out_size, void* d_ws, size_t ws_size,
                              hipStream_t stream)
{
  const float* x      = (const float*)d_in[0];
  const float* gate_w = (const float*)d_in[1];
  const float* gate_b = (const float*)d_in[2];
  const float* w1     = (const float*)d_in[3];
  const float* b1     = (const float*)d_in[4];
  const float* w2     = (const float*)d_in[5];
  const float* b2     = (const float*)d_in[6];
  const float* noise  = (const float*)d_in[7];
  float* out = (float*)d_out;

  if (ws_size < (size_t)(1 << 20)) return;   // cannot run safely; signals via failed bench

  char* ws = (char*)d_ws;
  // ws layout (bytes):
  const size_t CNT_OFF = 0;          // int counts[8]
  const size_t OFF_OFF = 64;         // int offs[9]
  const size_t LT_OFF  = 128;        // int  lists_tok[8][8192]   (256 KB)
  const size_t LP_OFF  = 262272;     // f32  lists_p  [8][8192]   (256 KB)
  const size_t PA_OFF  = 524416;     // f32  probs_all[8192][8]   (256 KB)
  const size_t XB_OFF  = 1048576;    // bf16 xb[8192][1024]       (16 MB)
  const size_t HB_OFF  = 17825792;   // bf16 h[16384][Hs]

  int* counts        = (int*)(ws + CNT_OFF);
  int* offs          = (int*)(ws + OFF_OFF);
  int* lists_tok     = (int*)(ws + LT_OFF);
  float* lists_p     = (float*)(ws + LP_OFF);
  float* probs_all   = (float*)(ws + PA_OFF);
  unsigned short* xb = (unsigned short*)(ws + XB_OFF);
  unsigned short* hbuf = (unsigned short*)(ws + HB_OFF);

  // pick H-slicing so h fits: h bytes = 16384 * (2048/nsl) * 2 = 64MB/nsl
  int nsl = 0;
  for (int cand = 1; cand <= 16; cand <<= 1) {
    if (ws_size >= HB_OFF + (size_t)67108864 / (size_t)cand) { nsl = cand; break; }
  }
  const bool do_xb = (ws_size >= HB_OFF);

  hipMemsetAsync(d_out, 0, (size_t)OUT_MAIN * sizeof(float), stream);
  hipMemsetAsync(ws + CNT_OFF, 0, 64, stream);

  k_gating<<<NTOK / 4, 256, 0, stream>>>(x, gate_w, gate_b, noise, out, counts,
                                         lists_tok, lists_p, probs_all,
                                         do_xb ? xb : (unsigned short*)nullptr);
  k_offs<<<1, 64, 0, stream>>>(counts, offs);
  k_aux<<<1, 256, 0, stream>>>(probs_all, out);

  if (nsl) {
    const int Hs = HID / nsl;
    for (int s = 0; s < nsl; ++s) {
      const int hb = s * Hs;
      dim3 g1(64, Hs / 128, NEXP);
      k_gemm<0><<<g1, 256, 0, stream>>>(xb, w1, b1, counts, offs, lists_tok, lists_p,
                                        hbuf, out, hb, Hs);
      dim3 g2(64, DIM / 128, NEXP);
      k_gemm<1><<<g2, 256, 0, stream>>>(hbuf, w2, b2, counts, offs, lists_tok, lists_p,
                                        hbuf, out, hb, Hs);
    }
  }
}